// Round 10
// baseline (48.498 us; speedup 1.0000x reference)
//
#include <hip/hip_runtime.h>
#include <math.h>

#define BATCH 4096
#define NROWS (2 * BATCH)      // 8192
#define D 128
#define DX 512

constexpr int NSPLIT = 8;
constexpr int SLOTS = NSPLIT * 2;   // row-partial slots (split x wc) = 16

// sqrt(2*log2(e)) — both Gram operands carry this, so dot == log2(exp(sim))
#define SCALE 1.698644f

// ws float offsets (every slot that is read is written every call; no atomics)
#define WS_PART   0                          // [NROWS][16] = 131072
#define WS_CP     131072                     // [c:64][j-1:32][wr:2][128] = 524288
#define WS_RECONP 655360                     // [512]
#define WS_ZRECP  (WS_RECONP + 512)          // [256]
#define WS_POSP   (WS_ZRECP + 256)           // [256]
#define WS_LSEP   (WS_POSP + 256)            // [64]
#define WS_NBF8   (WS_LSEP + 64)             // fp8[16][NROWS][8] chunk-transposed (1 MB)

typedef float f32x16 __attribute__((ext_vector_type(16)));
typedef long long i64;
typedef unsigned char u8;
typedef unsigned short u16;

__device__ __forceinline__ float wave_reduce(float v) {
    #pragma unroll
    for (int o = 32; o > 0; o >>= 1) v += __shfl_xor(v, o);
    return v;
}

// one wave per (i, i+B) pair: norms, chunk-transposed scaled-fp8 rows,
// zrecon & positives partials (f32 exact)
__global__ __launch_bounds__(256) void k_prep(const float* __restrict__ rep,
                                              float* __restrict__ ws) {
    const int w = threadIdx.x >> 6, l = threadIdx.x & 63;
    const int wg = blockIdx.x * 4 + w;          // 0..1023
    u8* nbf8 = (u8*)(ws + WS_NBF8);
    const int chunk = l >> 2, el = (l & 3) * 2; // lane's 2 elems live here
    float zacc = 0.f, pacc = 0.f;
    #pragma unroll
    for (int p = 0; p < 4; ++p) {
        const int i = wg + p * 1024;            // 0..4095
        float2 a = *reinterpret_cast<const float2*>(rep + i * D + l * 2);
        float2 b = *reinterpret_cast<const float2*>(rep + (i + BATCH) * D + l * 2);
        float dx = a.x - b.x, dy = a.y - b.y;
        float sa  = wave_reduce(a.x * a.x + a.y * a.y);
        float sb  = wave_reduce(b.x * b.x + b.y * b.y);
        float sab = wave_reduce(a.x * b.x + a.y * b.y);
        float sd  = wave_reduce(dx * dx + dy * dy);
        float ia = 1.0f / (sqrtf(sa) + 1e-8f);
        float ib = 1.0f / (sqrtf(sb) + 1e-8f);
        zacc += sd;
        pacc += sab * ia * ib;
        int pka = __builtin_amdgcn_cvt_pk_fp8_f32(a.x * ia * SCALE,
                                                  a.y * ia * SCALE, 0, false);
        int pkb = __builtin_amdgcn_cvt_pk_fp8_f32(b.x * ib * SCALE,
                                                  b.y * ib * SCALE, 0, false);
        *reinterpret_cast<u16*>(
            nbf8 + ((size_t)chunk * NROWS + i) * 8 + el) = (u16)pka;
        *reinterpret_cast<u16*>(
            nbf8 + ((size_t)chunk * NROWS + i + BATCH) * 8 + el) = (u16)pkb;
    }
    __shared__ float shz[4], shp[4];
    if (l == 0) { shz[w] = zacc; shp[w] = pacc; }
    __syncthreads();
    if (threadIdx.x == 0) {
        ws[WS_ZRECP + blockIdx.x] = shz[0] + shz[1] + shz[2] + shz[3];
        ws[WS_POSP + blockIdx.x] = 4.0f * (shp[0] + shp[1] + shp[2] + shp[3]);
    }
}

// Symmetric fp8 MFMA Gram: block (r,s) computes only tiles c = (r+j)&63 for
// its j-slice of {0..31} (+ j=32 when r<32). Off-diagonal tiles contribute
// row-sums (register-accumulated) AND column-partials (exp values are
// bit-identical to the transpose tile's). No LDS / no barriers in main loop.
// Each wave owns a 64x64 quadrant (4 independent MFMA chains).
__global__ __launch_bounds__(256, 2) void k_lse(const float4* __restrict__ xr,
                                                const float4* __restrict__ xo,
                                                float* __restrict__ ws) {
    const u8* __restrict__ nbf8 = (const u8*)(ws + WS_NBF8);
    const int tid = threadIdx.x;
    const int w = tid >> 6, l = tid & 63;
    const int wr = w >> 1, wc = w & 1;
    const int rblk = blockIdx.x;                 // 0..63
    const int s = blockIdx.y;                    // 0..7
    const int R0 = rblk * 128;
    const int fid = rblk * 8 + s;                // 0..511

    // ---- A fragments: 2 row-blocks of 32, registers, reused across tiles
    i64 afrag[2][8];
    #pragma unroll
    for (int rb = 0; rb < 2; ++rb) {
        const int lr = R0 + wr * 64 + rb * 32 + (l & 31);
        #pragma unroll
        for (int ss = 0; ss < 8; ++ss) {
            const int c = 2 * ss + (l >> 5);
            afrag[rb][ss] = *reinterpret_cast<const i64*>(
                nbf8 + ((size_t)c * NROWS + lr) * 8);
        }
    }

    float sumexp[2][16] = {};
    float racc = 0.f;

    // one tile: j = cyclic column offset; t = xrecon slot (-1: none)
    auto tile = [&](int j, int t) {
        const int cblk = (rblk + j) & 63;
        const int C0 = cblk * 128;

        // B fragments for this tile
        i64 buf[16];
        const int lc = C0 + wc * 64 + (l & 31);
        #pragma unroll
        for (int ss = 0; ss < 8; ++ss) {
            const int c = 2 * ss + (l >> 5);
            const u8* base = nbf8 + (size_t)c * NROWS * 8;
            buf[2 * ss]     = *reinterpret_cast<const i64*>(base + (size_t)lc * 8);
            buf[2 * ss + 1] = *reinterpret_cast<const i64*>(base + (size_t)(lc + 32) * 8);
        }

        // fused xrecon MSE: two float4-pairs per thread on tiles 0..3
        float4 ra0, rb0, ra1, rb1;
        if (t >= 0) {
            const int i0 = (fid * 8 + 2 * t) * 256 + tid;
            const int i1 = (fid * 8 + 2 * t + 1) * 256 + tid;
            ra0 = xr[i0]; rb0 = xo[i0];
            ra1 = xr[i1]; rb1 = xo[i1];
        }

        f32x16 acc[2][2] = {};
        #pragma unroll
        for (int ss = 0; ss < 8; ++ss) {
            acc[0][0] = __builtin_amdgcn_mfma_f32_32x32x16_fp8_fp8(
                afrag[0][ss], buf[2 * ss], acc[0][0], 0, 0, 0);
            acc[0][1] = __builtin_amdgcn_mfma_f32_32x32x16_fp8_fp8(
                afrag[0][ss], buf[2 * ss + 1], acc[0][1], 0, 0, 0);
            acc[1][0] = __builtin_amdgcn_mfma_f32_32x32x16_fp8_fp8(
                afrag[1][ss], buf[2 * ss], acc[1][0], 0, 0, 0);
            acc[1][1] = __builtin_amdgcn_mfma_f32_32x32x16_fp8_fp8(
                afrag[1][ss], buf[2 * ss + 1], acc[1][1], 0, 0, 0);
        }

        if (t >= 0) {
            float dx = ra0.x - rb0.x, dy = ra0.y - rb0.y;
            float dz = ra0.z - rb0.z, dw2 = ra0.w - rb0.w;
            racc += dx * dx + dy * dy + dz * dz + dw2 * dw2;
            dx = ra1.x - rb1.x; dy = ra1.y - rb1.y;
            dz = ra1.z - rb1.z; dw2 = ra1.w - rb1.w;
            racc += dx * dx + dy * dy + dz * dz + dw2 * dw2;
        }

        // acc == sim*log2(e) by operand scaling → exp(sim) = exp2(acc)
        const bool isdiag = (j == 0);
        float colacc[2] = {0.f, 0.f};
        #pragma unroll
        for (int rb = 0; rb < 2; ++rb) {
            #pragma unroll
            for (int cb = 0; cb < 2; ++cb) {
                const bool dmask = isdiag && ((2 * wr + rb) == (2 * wc + cb));
                #pragma unroll
                for (int r = 0; r < 16; ++r) {
                    float e = __builtin_amdgcn_exp2f(acc[rb][cb][r]);
                    if (dmask) {
                        const int rrow = (r & 3) + 8 * (r >> 2) + 4 * (l >> 5);
                        if (rrow == (l & 31)) e = 0.0f;
                    }
                    sumexp[rb][r] += e;
                    colacc[cb] += e;
                }
            }
        }
        if (!isdiag) {
            #pragma unroll
            for (int cb = 0; cb < 2; ++cb) {
                float v = colacc[cb] + __shfl_xor(colacc[cb], 32);
                if (l < 32) {
                    const int col = wc * 64 + cb * 32 + l;
                    ws[WS_CP + (((cblk * 32) + (j - 1)) * 2 + wr) * 128 + col] = v;
                }
            }
        }
    };

    if (s < 7) {
        const int jb = 4 * s + 1;                // j = 1..28
        #pragma unroll
        for (int t = 0; t < 4; ++t) tile(jb + t, t);
    } else {
        tile(29, 0); tile(30, 1); tile(31, 2); tile(0, 3);
        if (rblk < 32) tile(32, -1);             // pair {r, r+32} once
    }

    // row partials: reduce over the 32 column-lanes
    #pragma unroll
    for (int rb = 0; rb < 2; ++rb) {
        #pragma unroll
        for (int r = 0; r < 16; ++r) {
            float v = sumexp[rb][r];
            #pragma unroll
            for (int m = 1; m <= 16; m <<= 1) v += __shfl_xor(v, m);
            sumexp[rb][r] = v;
        }
    }
    if ((l & 31) == 0) {
        #pragma unroll
        for (int rb = 0; rb < 2; ++rb) {
            #pragma unroll
            for (int r = 0; r < 16; ++r) {
                const int row = R0 + wr * 64 + rb * 32
                              + (r & 3) + 8 * (r >> 2) + 4 * (l >> 5);
                ws[WS_PART + row * SLOTS + s * 2 + wc] = sumexp[rb][r];
            }
        }
    }

    // recon partial for this block
    racc = wave_reduce(racc);
    __shared__ float shr[4];
    if (l == 0) shr[w] = racc;
    __syncthreads();
    if (tid == 0) ws[WS_RECONP + fid] = shr[0] + shr[1] + shr[2] + shr[3];
}

// per row-block q: rowsum = 16 RP slots + CP[j=1..31(+32 if q>=32)][wr];
// then log + block partial
__global__ __launch_bounds__(256) void k_rowlse(float* __restrict__ ws) {
    const int q = blockIdx.x, tid = threadIdx.x;
    const int col = tid & 127, h = tid >> 7;     // 2 threads per row
    const int row = q * 128 + col;
    float ssum = 0.f;
    #pragma unroll
    for (int ss = 0; ss < SLOTS / 2; ++ss)
        ssum += ws[WS_PART + row * SLOTS + 2 * ss + h];
    const float* cpq = ws + WS_CP + (size_t)q * 32 * 2 * 128;
    for (int j = 1; j <= 31; ++j)
        ssum += cpq[((j - 1) * 2 + h) * 128 + col];
    if (q >= 32)
        ssum += cpq[(31 * 2 + h) * 128 + col];
    __shared__ float red[128];
    if (h) red[col] = ssum;
    __syncthreads();
    float lg = 0.f;
    if (!h) lg = logf(ssum + red[col]);
    lg = wave_reduce(lg);
    __shared__ float sh[4];
    const int w = tid >> 6, l = tid & 63;
    if (l == 0) sh[w] = lg;
    __syncthreads();
    if (tid == 0) ws[WS_LSEP + q] = sh[0] + sh[1] + sh[2] + sh[3];
}

__global__ __launch_bounds__(256) void k_combine(const float* __restrict__ ws,
                                                 float* __restrict__ out) {
    const int tid = threadIdx.x;
    float lacc = (tid < 64) ? ws[WS_LSEP + tid] : 0.f;
    float racc = ws[WS_RECONP + tid] + ws[WS_RECONP + 256 + tid];
    float zacc = ws[WS_ZRECP + tid];
    float pacc = ws[WS_POSP + tid];

    lacc = wave_reduce(lacc);
    racc = wave_reduce(racc);
    zacc = wave_reduce(zacc);
    pacc = wave_reduce(pacc);

    __shared__ float sh[4][4];
    const int w = tid >> 6, l = tid & 63;
    if (l == 0) { sh[0][w] = lacc; sh[1][w] = racc; sh[2][w] = zacc; sh[3][w] = pacc; }
    __syncthreads();
    if (tid == 0) {
        float lse = sh[0][0] + sh[0][1] + sh[0][2] + sh[0][3];
        float rec = (sh[1][0] + sh[1][1] + sh[1][2] + sh[1][3]) / (float)(NROWS * DX);
        float zre = (sh[2][0] + sh[2][1] + sh[2][2] + sh[2][3]) / (float)(BATCH * D);
        float pos = sh[3][0] + sh[3][1] + sh[3][2] + sh[3][3];
        float closs = (lse - pos) / (float)NROWS;
        out[0] = rec + closs + zre;
        out[1] = closs;
        out[2] = rec;
        out[3] = zre;
    }
}

extern "C" void kernel_launch(void* const* d_in, const int* in_sizes, int n_in,
                              void* d_out, int out_size, void* d_ws, size_t ws_size,
                              hipStream_t stream) {
    const float* rep = (const float*)d_in[0];
    const float4* xr = (const float4*)d_in[1];
    const float4* xo = (const float4*)d_in[2];
    float* out = (float*)d_out;
    float* ws = (float*)d_ws;

    k_prep<<<256, 256, 0, stream>>>(rep, ws);
    dim3 grid(64, NSPLIT);
    k_lse<<<grid, 256, 0, stream>>>(xr, xo, ws);
    k_rowlse<<<64, 256, 0, stream>>>(ws);
    k_combine<<<1, 256, 0, stream>>>(ws, out);
}

// Round 11
// 33.961 us; speedup vs baseline: 1.4280x; 1.4280x over previous
//
#include <hip/hip_runtime.h>
#include <math.h>

#define BATCH 4096
#define NROWS (2 * BATCH)      // 8192
#define D 128
#define DX 512

constexpr int NSPLIT = 8;
constexpr int NT = 8;               // 128-col tiles per split (1024 cols)
constexpr int SLOTS = NSPLIT * 2;   // row-partial slots (split x wc) = 16

// sqrt(2*log2(e)) — both Gram operands carry this, so dot == log2(exp(sim))
#define SCALE 1.698644f

// ws float offsets (every slot that is read is written every call; no atomics)
#define WS_PART   0                          // [NROWS][SLOTS] = 131072
#define WS_RECONP 131072                     // [512]
#define WS_ZRECP  (WS_RECONP + 512)          // [256]
#define WS_POSP   (WS_ZRECP + 256)           // [256]
#define WS_LSEP   (WS_POSP + 256)            // [64]
#define WS_NBF8   (WS_LSEP + 64)             // fp8[16][NROWS][8] chunk-transposed (1 MB)

typedef float f32x16 __attribute__((ext_vector_type(16)));
typedef long long i64;
typedef unsigned char u8;
typedef unsigned short u16;

__device__ __forceinline__ float wave_reduce(float v) {
    #pragma unroll
    for (int o = 32; o > 0; o >>= 1) v += __shfl_xor(v, o);
    return v;
}

// one wave per (i, i+B) pair: norms, chunk-transposed scaled-fp8 rows,
// zrecon & positives partials (f32 exact)
__global__ __launch_bounds__(256) void k_prep(const float* __restrict__ rep,
                                              float* __restrict__ ws) {
    const int w = threadIdx.x >> 6, l = threadIdx.x & 63;
    const int wg = blockIdx.x * 4 + w;          // 0..1023
    u8* nbf8 = (u8*)(ws + WS_NBF8);
    const int chunk = l >> 2, el = (l & 3) * 2; // lane's 2 elems live here
    float zacc = 0.f, pacc = 0.f;
    #pragma unroll
    for (int p = 0; p < 4; ++p) {
        const int i = wg + p * 1024;            // 0..4095
        float2 a = *reinterpret_cast<const float2*>(rep + i * D + l * 2);
        float2 b = *reinterpret_cast<const float2*>(rep + (i + BATCH) * D + l * 2);
        float dx = a.x - b.x, dy = a.y - b.y;
        float sa  = wave_reduce(a.x * a.x + a.y * a.y);
        float sb  = wave_reduce(b.x * b.x + b.y * b.y);
        float sab = wave_reduce(a.x * b.x + a.y * b.y);
        float sd  = wave_reduce(dx * dx + dy * dy);
        float ia = 1.0f / (sqrtf(sa) + 1e-8f);
        float ib = 1.0f / (sqrtf(sb) + 1e-8f);
        zacc += sd;
        pacc += sab * ia * ib;
        int pka = __builtin_amdgcn_cvt_pk_fp8_f32(a.x * ia * SCALE,
                                                  a.y * ia * SCALE, 0, false);
        int pkb = __builtin_amdgcn_cvt_pk_fp8_f32(b.x * ib * SCALE,
                                                  b.y * ib * SCALE, 0, false);
        *reinterpret_cast<u16*>(
            nbf8 + ((size_t)chunk * NROWS + i) * 8 + el) = (u16)pka;
        *reinterpret_cast<u16*>(
            nbf8 + ((size_t)chunk * NROWS + i + BATCH) * 8 + el) = (u16)pkb;
    }
    __shared__ float shz[4], shp[4];
    if (l == 0) { shz[w] = zacc; shp[w] = pacc; }
    __syncthreads();
    if (threadIdx.x == 0) {
        ws[WS_ZRECP + blockIdx.x] = shz[0] + shz[1] + shz[2] + shz[3];
        ws[WS_POSP + blockIdx.x] = 4.0f * (shp[0] + shp[1] + shp[2] + shp[3]);
    }
}

// fp8 MFMA Gram + fused exp2-rowsum + fused xrecon-MSE partial.
// No LDS / no barriers. 2x2 waves per 128x128 tile; each wave owns a 64x64
// quadrant processed as 16 half-tiles (64x32, 32 AGPR). Software pipeline
// with in-order issue exploited: MFMA(half s+1) issues BEFORE exp(half s),
// so the exp/VALU tail of each half fills the matrix pipe's shadow instead
// of blocking the next MFMA batch. B-fragments, recon pairs, and acc states
// are all register double-buffered with static names (no runtime indexing).
__global__ __launch_bounds__(256, 2) void k_lse(const float4* __restrict__ xr,
                                                const float4* __restrict__ xo,
                                                float* __restrict__ ws) {
    const u8* __restrict__ nbf8 = (const u8*)(ws + WS_NBF8);
    const int tid = threadIdx.x;
    const int w = tid >> 6, l = tid & 63;
    const int wr = w >> 1, wc = w & 1;
    const int rblk = blockIdx.x;                 // 0..63
    const int split = blockIdx.y;                // 0..7
    const int R0 = rblk * 128;
    const int fid = rblk + 64 * split;           // 0..511

    // ---- A fragments: 2 row-blocks of 32, registers, reused across tiles
    i64 afrag[2][8];
    #pragma unroll
    for (int rb = 0; rb < 2; ++rb) {
        const int lr = R0 + wr * 64 + rb * 32 + (l & 31);
        #pragma unroll
        for (int k = 0; k < 8; ++k) {
            const int c = 2 * k + (l >> 5);
            afrag[rb][k] = *reinterpret_cast<const i64*>(
                nbf8 + ((size_t)c * NROWS + lr) * 8);
        }
    }

    i64 bufA[8], bufB[8];
    f32x16 accA[2], accB[2];
    float4 ra, rb2;
    float sumexp[2][16] = {};
    float racc = 0.f;

    // half index s = 2*t + cb  (t = 128-col tile, cb = 32-col half of quadrant)
    auto loadB = [&](i64 (&buf)[8], int s) {
        const int lc = split * (NT * 128) + (s >> 1) * 128 + wc * 64
                     + (s & 1) * 32 + (l & 31);
        #pragma unroll
        for (int k = 0; k < 8; ++k) {
            const int c = 2 * k + (l >> 5);
            buf[k] = *reinterpret_cast<const i64*>(
                nbf8 + ((size_t)c * NROWS + lc) * 8);
        }
    };

    auto mfmaH = [&](i64 (&buf)[8], f32x16 (&acc)[2]) {
        acc[0] = (f32x16)(0.f);
        acc[1] = (f32x16)(0.f);
        #pragma unroll
        for (int k = 0; k < 8; ++k) {
            acc[0] = __builtin_amdgcn_mfma_f32_32x32x16_fp8_fp8(
                afrag[0][k], buf[k], acc[0], 0, 0, 0);
            acc[1] = __builtin_amdgcn_mfma_f32_32x32x16_fp8_fp8(
                afrag[1][k], buf[k], acc[1], 0, 0, 0);
        }
    };

    // acc == sim*log2(e) by operand scaling → exp(sim) = exp2(acc)
    auto expH = [&](f32x16 (&acc)[2], int s) {
        const int t = s >> 1, cb = s & 1;
        const bool diagt = (split * NT + t) == rblk;
        #pragma unroll
        for (int rb = 0; rb < 2; ++rb) {
            const bool dmask = diagt && ((2 * wr + rb) == (2 * wc + cb));
            #pragma unroll
            for (int r = 0; r < 16; ++r) {
                float e = __builtin_amdgcn_exp2f(acc[rb][r]);
                if (dmask) {
                    const int rrow = (r & 3) + 8 * (r >> 2) + 4 * (l >> 5);
                    if (rrow == (l & 31)) e = 0.0f;
                }
                sumexp[rb][r] += e;
            }
        }
    };

    // ---- prologue
    loadB(bufA, 0);
    loadB(bufB, 1);
    {
        const int ri = fid * 2048 + tid;         // recon pair 0
        ra = xr[ri]; rb2 = xo[ri];
    }
    mfmaH(bufA, accA);                           // half 0

    // ---- pipelined main loop: one iteration = 2 halves = 1 recon pair
    #pragma unroll
    for (int s = 0; s < 16; s += 2) {
        const int k = s >> 1;                    // recon pair index
        if (s + 2 < 16) loadB(bufA, s + 2);      // prefetch even half
        mfmaH(bufB, accB);                       // MFMA half s+1 (matrix pipe)
        {                                        // consume recon pair k ...
            float dx = ra.x - rb2.x, dy = ra.y - rb2.y;
            float dz = ra.z - rb2.z, dw2 = ra.w - rb2.w;
            racc += dx * dx + dy * dy + dz * dz + dw2 * dw2;
        }
        if (k + 1 < 8) {                         // ... then reload in place
            const int ri = fid * 2048 + (k + 1) * 256 + tid;
            ra = xr[ri]; rb2 = xo[ri];
        }
        expH(accA, s);                           // exp half s (VALU, overlaps)
        if (s + 3 < 16) loadB(bufB, s + 3);      // prefetch odd half
        if (s + 2 < 16) mfmaH(bufA, accA);       // MFMA half s+2
        expH(accB, s + 1);                       // exp half s+1
    }

    // reduce over the 32 column-lanes; lanes 0 and 32 hold row sums
    #pragma unroll
    for (int rb = 0; rb < 2; ++rb) {
        #pragma unroll
        for (int r = 0; r < 16; ++r) {
            float v = sumexp[rb][r];
            #pragma unroll
            for (int m = 1; m <= 16; m <<= 1) v += __shfl_xor(v, m);
            sumexp[rb][r] = v;
        }
    }
    if ((l & 31) == 0) {
        #pragma unroll
        for (int rb = 0; rb < 2; ++rb) {
            #pragma unroll
            for (int r = 0; r < 16; ++r) {
                const int row = R0 + wr * 64 + rb * 32
                              + (r & 3) + 8 * (r >> 2) + 4 * (l >> 5);
                ws[WS_PART + row * SLOTS + split * 2 + wc] = sumexp[rb][r];
            }
        }
    }

    // recon partial for this block
    racc = wave_reduce(racc);
    __shared__ float shr[4];
    if (l == 0) shr[w] = racc;
    __syncthreads();
    if (tid == 0) ws[WS_RECONP + fid] = shr[0] + shr[1] + shr[2] + shr[3];
}

// per row-block q (128 rows): sum the 16 slots per row, log, block partial
__global__ __launch_bounds__(256) void k_rowlse(float* __restrict__ ws) {
    const int q = blockIdx.x, tid = threadIdx.x;
    const int j = tid & 127, h = tid >> 7;       // 2 threads per row
    const int row = q * 128 + j;
    float s = 0.f;
    #pragma unroll
    for (int ss = 0; ss < SLOTS / 2; ++ss)
        s += ws[WS_PART + row * SLOTS + 2 * ss + h];
    __shared__ float red[128];
    if (h) red[j] = s;
    __syncthreads();
    float lg = 0.f;
    if (!h) lg = logf(s + red[j]);
    lg = wave_reduce(lg);
    __shared__ float sh[4];
    const int w = tid >> 6, l = tid & 63;
    if (l == 0) sh[w] = lg;
    __syncthreads();
    if (tid == 0) ws[WS_LSEP + q] = sh[0] + sh[1] + sh[2] + sh[3];
}

__global__ __launch_bounds__(256) void k_combine(const float* __restrict__ ws,
                                                 float* __restrict__ out) {
    const int tid = threadIdx.x;
    float lacc = (tid < 64) ? ws[WS_LSEP + tid] : 0.f;
    float racc = ws[WS_RECONP + tid] + ws[WS_RECONP + 256 + tid];
    float zacc = ws[WS_ZRECP + tid];
    float pacc = ws[WS_POSP + tid];

    lacc = wave_reduce(lacc);
    racc = wave_reduce(racc);
    zacc = wave_reduce(zacc);
    pacc = wave_reduce(pacc);

    __shared__ float sh[4][4];
    const int w = tid >> 6, l = tid & 63;
    if (l == 0) { sh[0][w] = lacc; sh[1][w] = racc; sh[2][w] = zacc; sh[3][w] = pacc; }
    __syncthreads();
    if (tid == 0) {
        float lse = sh[0][0] + sh[0][1] + sh[0][2] + sh[0][3];
        float rec = (sh[1][0] + sh[1][1] + sh[1][2] + sh[1][3]) / (float)(NROWS * DX);
        float zre = (sh[2][0] + sh[2][1] + sh[2][2] + sh[2][3]) / (float)(BATCH * D);
        float pos = sh[3][0] + sh[3][1] + sh[3][2] + sh[3][3];
        float closs = (lse - pos) / (float)NROWS;
        out[0] = rec + closs + zre;
        out[1] = closs;
        out[2] = rec;
        out[3] = zre;
    }
}

extern "C" void kernel_launch(void* const* d_in, const int* in_sizes, int n_in,
                              void* d_out, int out_size, void* d_ws, size_t ws_size,
                              hipStream_t stream) {
    const float* rep = (const float*)d_in[0];
    const float4* xr = (const float4*)d_in[1];
    const float4* xo = (const float4*)d_in[2];
    float* out = (float*)d_out;
    float* ws = (float*)d_ws;

    k_prep<<<256, 256, 0, stream>>>(rep, ws);
    dim3 grid(64, NSPLIT);
    k_lse<<<grid, 256, 0, stream>>>(xr, xo, ws);
    k_rowlse<<<64, 256, 0, stream>>>(ws);
    k_combine<<<1, 256, 0, stream>>>(ws, out);
}